// Round 1
// baseline (490.648 us; speedup 1.0000x reference)
//
#include <hip/hip_runtime.h>

// out = att @ h  with att = where(adj>0, s1[i]+s2[j], -9e15).
// out[i,k] = -9e15 * (T[k] - Am[i,k]),  Am = (adj>0) @ h,  T = colsum(h)
// Am is a bf16 MFMA GEMM with an exact {0,1} A-matrix; 9e15 stays fp32.
//
// R7: rocprof top-5 are all 1GB harness fills (~160us); every kernel of
// ours is below that. Remaining structural cost: splitK=8 partials
// (P 64MB wr + K4 128MB rd/wr) and a latency-serialized K3 (R6: prefetch
// depth ~1.3 iters << 900cyc HBM latency). Rewrite K3 as splitK=1:
//  - grid 256 WG (1/CU) x 4 waves, wave = 32 rows x 64 cols (acc = 32 VGPR)
//  - 256 iters x 32 j, adj in a 4-slot REGISTER ring: tile issued at iter
//    it is consumed at it+2 (~2.3 iters ~ 1000 cyc in flight > HBM latency)
//  - B double-buffered in regs (depth 1; hP mtile is L2-hot since all WGs
//    sweep it in lockstep)
//  - wave-private double-buffered LDS, proven [jgrp4][row32][8] layout,
//    conflict-free b128 frag reads, no barriers
//  - epilogue writes out = -9e15*(T[n]-acc) directly: no P, no K4, no k2b.

#define NEG_BIG (-9000000000000000.0f)

typedef __bf16 bf16x8 __attribute__((ext_vector_type(8)));
typedef float f32x16 __attribute__((ext_vector_type(16)));

static __device__ __forceinline__ unsigned short f2bf(float f) {
  unsigned u = __builtin_bit_cast(unsigned, f);
  u = u + 0x7FFFu + ((u >> 16) & 1u);   // RNE
  return (unsigned short)(u >> 16);
}
static __device__ __forceinline__ float bfbits2f(unsigned hi16) {
  return __builtin_bit_cast(float, hi16 << 16);
}
static __device__ __forceinline__ unsigned pk2(float a, float b) {
  return (unsigned)f2bf(a) | ((unsigned)f2bf(b) << 16);
}
// two adj ints {0,1} -> packed bf16 pair {0.0,1.0}
static __device__ __forceinline__ unsigned m2(int a, int b) {
  return (unsigned)(a + (b << 16)) * 0x3F80u;
}
static __device__ __forceinline__ bf16x8 asbf(int4 q) {
  return __builtin_bit_cast(bf16x8, q);
}
static __device__ __forceinline__ f32x16 mfma(bf16x8 a, int4 b, f32x16 c) {
  return __builtin_amdgcn_mfma_f32_32x32x16_bf16(a, asbf(b), c, 0, 0, 0);
}

// K1a: WT[n][k] = bf16(W[k][n]); W is 512x256 row-major. Also zeroes T.
__global__ void k1a_wt(const float* __restrict__ W, unsigned short* __restrict__ WT,
                       float* __restrict__ T) {
  const int i = blockIdx.x * 256 + threadIdx.x;
  const int k = i >> 8, n = i & 255;
  WT[n * 512 + k] = f2bf(W[i]);
  if (blockIdx.x == 0) T[threadIdx.x] = 0.f;
}

// K1b: h = x @ W. x tile (32 rows x 512 k) staged through LDS in
// fragment-ready bf16 layout, then 32 MFMA k-steps.
__global__ __launch_bounds__(256) void k1b_h(const float* __restrict__ x,
    const unsigned short* __restrict__ WT, unsigned short* __restrict__ hP) {
  __shared__ unsigned short XS[64 * 264];
  const int t = threadIdx.x;
  const int mt = blockIdx.x;
  const int m0 = mt << 5;
  const int row = t >> 3, c7 = t & 7;
  const float* xr = x + (size_t)(m0 + row) * 512 + c7 * 4;
  const int gb = c7 >> 1, off = (t & 1) * 4;
#pragma unroll
  for (int j = 0; j < 16; ++j) {
    float4 v = *(const float4*)(xr + 32 * j);
    *(uint2*)&XS[(gb + 4 * j) * 264 + row * 8 + off] =
        make_uint2(pk2(v.x, v.y), pk2(v.z, v.w));
  }
  __syncthreads();
  const int w = t >> 6, l = t & 63, l31 = l & 31, lh = l >> 5;
  f32x16 acc0, acc1;
  for (int i = 0; i < 16; ++i) { acc0[i] = 0.f; acc1[i] = 0.f; }
  const int nt0 = w * 2;
  const unsigned short* w0 = WT + (size_t)(nt0 * 32 + l31) * 512 + lh * 8;
  const unsigned short* w1 = w0 + 32 * 512;
  const char* XB = (const char*)XS + lh * 528 + l31 * 16;
#pragma unroll 4
  for (int ks = 0; ks < 32; ++ks) {
    bf16x8 Af = *(const bf16x8*)(XB + ks * 1056);
    int4 b0 = *(const int4*)(w0 + ks * 16);
    int4 b1 = *(const int4*)(w1 + ks * 16);
    acc0 = mfma(Af, b0, acc0);
    acc1 = mfma(Af, b1, acc1);
  }
#pragma unroll
  for (int reg = 0; reg < 16; ++reg) {
    const int mm = (reg & 3) + 8 * (reg >> 2) + 4 * lh;      // C/D row map
    hP[(size_t)mt * 8192 + (nt0 * 32 + l31) * 32 + mm] = f2bf(acc0[reg]);
    hP[(size_t)mt * 8192 + ((nt0 + 1) * 32 + l31) * 32 + mm] = f2bf(acc1[reg]);
  }
}

// K2: T[n] += partial colsum of h. Block b sums panel block b (coalesced).
__global__ __launch_bounds__(256) void k2_colsum(const unsigned short* __restrict__ hP,
                                                 float* __restrict__ T) {
  const int t = threadIdx.x;
  const int b = blockIdx.x;
  const int4* p = (const int4*)(hP + (size_t)b * 8192 + t * 32);
  int4 q0 = p[0], q1 = p[1], q2 = p[2], q3 = p[3];
  float s = 0.f;
  const unsigned* u0 = (const unsigned*)&q0;
  const unsigned* u1 = (const unsigned*)&q1;
  const unsigned* u2 = (const unsigned*)&q2;
  const unsigned* u3 = (const unsigned*)&q3;
#pragma unroll
  for (int i = 0; i < 4; ++i) {
    s += bfbits2f(u0[i] & 0xFFFFu) + bfbits2f(u0[i] >> 16);
    s += bfbits2f(u1[i] & 0xFFFFu) + bfbits2f(u1[i] >> 16);
    s += bfbits2f(u2[i] & 0xFFFFu) + bfbits2f(u2[i] >> 16);
    s += bfbits2f(u3[i] & 0xFFFFu) + bfbits2f(u3[i] >> 16);
  }
  atomicAdd(&T[t], s);
}

// K3: out = -9e15*(T - (adj>0)@h), splitK=1. Grid 256 WG x 4 waves.
// WG = 32 rows x 256 cols; wave w = 32 rows x cols [w*64, w*64+64).
// 256 iters of 32 j. adj tile (32r x 32j = 4 int4/lane) rides a 4-slot
// register ring (depth ~2.3 iters in flight), is packed as {0,1} bf16
// into wave-private double-buffered LDS [jgrp4][row32][8] (conflict-free
// b128 frag reads), B frags double-buffered in regs. No barriers.
__global__ __launch_bounds__(256) void k3_att(const int* __restrict__ adj,
    const unsigned short* __restrict__ hP, const float* __restrict__ T,
    float* __restrict__ out) {
  __shared__ unsigned short S[4][2][1024];   // [wave][buf][jgrp][row][8]
  const int t = threadIdx.x, blk = blockIdx.x;
  const int w = t >> 6, l = t & 63, l31 = l & 31, lh = l >> 5;
  const int r0 = blk * 32;

  // adj staging: lane -> row (l>>3) (+8 per q), 4 j at (l&7)*4
  const int* aB = adj + (size_t)(r0 + (l >> 3)) * 8192 + (l & 7) * 4;
  // LDS pack target (shorts): jgrp=(l&7)>>1, row=l>>3 (+8 per q), off=(l&1)*4
  const int woff = ((l & 7) >> 1) * 256 + (l >> 3) * 8 + (l & 1) * 4;
  // B-frag base: + it*8192; nt at +1024; ks at +16
  const unsigned short* hB = hP + (size_t)(w * 64 + l31) * 32 + lh * 8;
  // A-frag read base (bytes): jgrp = ks*2+lh -> +ks*1024
  const int fr = lh * 512 + l31 * 16;
  unsigned short* const Sw0 = &S[w][0][0];
  unsigned short* const Sw1 = &S[w][1][0];

  f32x16 acc0, acc1;
#pragma unroll
  for (int i = 0; i < 16; ++i) { acc0[i] = 0.f; acc1[i] = 0.f; }

  int4 gA0[4], gA1[4], gA2[4], gA3[4], BvA[4], BvB[4];

#define ALOAD(it, g)                                                        \
  _Pragma("unroll")                                                         \
  for (int q = 0; q < 4; ++q)                                               \
    g[q] = *(const int4*)(aB + (size_t)q * 65536 + (it) * 32);
#define APACK(buf, g)                                                       \
  _Pragma("unroll")                                                         \
  for (int q = 0; q < 4; ++q)                                               \
    *(uint2*)&buf[woff + q * 64] =                                          \
        make_uint2(m2(g[q].x, g[q].y), m2(g[q].z, g[q].w));
#define BLOAD(it, Bv)                                                       \
  {                                                                         \
    const unsigned short* hb = hB + (size_t)(it) * 8192;                    \
    Bv[0] = *(const int4*)(hb);                                             \
    Bv[1] = *(const int4*)(hb + 1024);                                      \
    Bv[2] = *(const int4*)(hb + 16);                                        \
    Bv[3] = *(const int4*)(hb + 1024 + 16);                                 \
  }
#define COMP(buf, Bv)                                                       \
  {                                                                         \
    const char* Ab = (const char*)(buf) + fr;                               \
    bf16x8 A0_ = *(const bf16x8*)(Ab);                                      \
    bf16x8 A1_ = *(const bf16x8*)(Ab + 1024);                               \
    acc0 = mfma(A0_, Bv[0], acc0);                                          \
    acc1 = mfma(A0_, Bv[1], acc1);                                          \
    acc0 = mfma(A1_, Bv[2], acc0);                                          \
    acc1 = mfma(A1_, Bv[3], acc1);                                          \
  }

  // prologue: fill ring (adj 0..2), pack adj(0), B(0)
  ALOAD(0, gA0)
  APACK(Sw0, gA0)
  ALOAD(1, gA1)
  ALOAD(2, gA2)
  BLOAD(0, BvA)

  // ring invariant at block top: gA1=adj(it+1), gA2=adj(it+2); gA0/gA3 free.
#pragma unroll 1
  for (int it = 0; it < 256; it += 4) {
    BLOAD(it + 1, BvB)
    APACK(Sw1, gA1)                        // adj(it+1)
    if (it + 3 < 256) { ALOAD(it + 3, gA3) }
    COMP(Sw0, BvA)                         // adj(it) * B(it)

    if (it + 2 < 256) { BLOAD(it + 2, BvA) }
    if (it + 2 < 256) { APACK(Sw0, gA2) }  // adj(it+2)
    if (it + 4 < 256) { ALOAD(it + 4, gA0) }
    COMP(Sw1, BvB)                         // adj(it+1) * B(it+1)

    if (it + 3 < 256) { BLOAD(it + 3, BvB) }
    if (it + 3 < 256) { APACK(Sw1, gA3) }  // adj(it+3)
    if (it + 5 < 256) { ALOAD(it + 5, gA1) }
    if (it + 2 < 256) { COMP(Sw0, BvA) }   // adj(it+2) * B(it+2)

    if (it + 4 < 256) { BLOAD(it + 4, BvA) }
    if (it + 4 < 256) { APACK(Sw0, gA0) }  // adj(it+4)
    if (it + 6 < 256) { ALOAD(it + 6, gA2) }
    if (it + 3 < 256) { COMP(Sw1, BvB) }   // adj(it+3) * B(it+3)
  }
#undef ALOAD
#undef APACK
#undef BLOAD
#undef COMP

  // epilogue: out[rr][cc] = -9e15 * (T[cc] - Am[rr][cc]); single write.
  const int cb = w * 64 + l31;
  {
    const float tv = T[cb];
#pragma unroll
    for (int reg = 0; reg < 16; ++reg) {
      const int rr = r0 + (reg & 3) + 8 * (reg >> 2) + 4 * lh;
      out[(size_t)rr * 256 + cb] = NEG_BIG * (tv - acc0[reg]);
    }
  }
  {
    const float tv = T[cb + 32];
#pragma unroll
    for (int reg = 0; reg < 16; ++reg) {
      const int rr = r0 + (reg & 3) + 8 * (reg >> 2) + 4 * lh;
      out[(size_t)rr * 256 + cb + 32] = NEG_BIG * (tv - acc1[reg]);
    }
  }
}

extern "C" void kernel_launch(void* const* d_in, const int* in_sizes, int n_in,
                              void* d_out, int out_size, void* d_ws, size_t ws_size,
                              hipStream_t stream) {
  const float* x = (const float*)d_in[0];     // 8192 x 512
  const float* W = (const float*)d_in[1];     // 512 x 256
  // d_in[2] ('a') unused: its contribution is ~1e4 vs threshold ~9e16.
  const int* adj = (const int*)d_in[3];       // 8192 x 8192 int32 {0,1}
  float* out = (float*)d_out;                 // 8192 x 256 fp32
  char* ws = (char*)d_ws;
  unsigned short* WT = (unsigned short*)(ws);             // 256 KB
  unsigned short* hP = (unsigned short*)(ws + (1 << 20)); // 4 MB panel
  float* T = (float*)(ws + (6 << 20));                    // 1 KB

  k1a_wt<<<512, 256, 0, stream>>>(W, WT, T);
  k1b_h<<<256, 256, 0, stream>>>(x, WT, hP);
  k2_colsum<<<256, 256, 0, stream>>>(hP, T);
  k3_att<<<256, 256, 0, stream>>>(adj, hP, T, out);
}

// Round 2
// 441.983 us; speedup vs baseline: 1.1101x; 1.1101x over previous
//
#include <hip/hip_runtime.h>

// out = att @ h  with att = where(adj>0, s1[i]+s2[j], -9e15).
// out[i,k] = -9e15 * (T[k] - Am[i,k]),  Am = (adj>0) @ h,  T = colsum(h)
//
// R8: K3-reads-adj-directly is latency-bound (816 GB/s, 1 wave/SIMD, VGPR
// mis-allocation collapsed the prefetch ring twice: R5/R6 and R7). Split:
//  - K0: adj (256MB) -> 1-bit mask (8MB) via __ballot. Pure streaming at
//    32 waves/CU => runs at fill-kernel BW (~6.5 TB/s, ~43us). Only kernel
//    touching the 256MB.
//  - K3: bitmask (L2-hot) -> A-frags expanded IN REGISTERS (no LDS in the
//    main loop: no bank conflicts, no lgkm waits, nothing to mis-schedule).
//    Wave = 64r x 64c, WG = 2 col-halves x 2 j-splits (in-WG splitK=2,
//    combined via 32KB LDS at the epilogue), grid 256 = 1 WG/CU.
//    B (hP) double-buffered in regs from L2 (512MB total @ L2 BW ~ 15us).
//
// Bitmask format (per row, 32 blocks of 256 j): block b = 4 u64 [c=0..3],
// bit l of u64 c = adj[i][b*256 + 4l + c]  (ballot over int4 lanes).

#define NEG_BIG (-9000000000000000.0f)

typedef __bf16 bf16x8 __attribute__((ext_vector_type(8)));
typedef float f32x16 __attribute__((ext_vector_type(16)));

static __device__ __forceinline__ unsigned short f2bf(float f) {
  unsigned u = __builtin_bit_cast(unsigned, f);
  u = u + 0x7FFFu + ((u >> 16) & 1u);   // RNE
  return (unsigned short)(u >> 16);
}
static __device__ __forceinline__ float bfbits2f(unsigned hi16) {
  return __builtin_bit_cast(float, hi16 << 16);
}
static __device__ __forceinline__ unsigned pk2(float a, float b) {
  return (unsigned)f2bf(a) | ((unsigned)f2bf(b) << 16);
}
static __device__ __forceinline__ bf16x8 asbf(int4 q) {
  return __builtin_bit_cast(bf16x8, q);
}
static __device__ __forceinline__ f32x16 mfma(bf16x8 a, int4 b, f32x16 c) {
  return __builtin_amdgcn_mfma_f32_32x32x16_bf16(a, asbf(b), c, 0, 0, 0);
}
// packed bf16 pair {bit da[p], bit db[p]} -> {0.0,1.0}x2
static __device__ __forceinline__ unsigned bp(unsigned da, unsigned db, int p) {
  return (((da >> p) & 1u) | (((db >> p) & 1u) << 16)) * 0x3F80u;
}
// A-frag (8 bf16) for one 16-k-step from the 4 ballot dwords; p0 = bit base
static __device__ __forceinline__ bf16x8 mkfrag(unsigned dA, unsigned dB,
                                                unsigned dC, unsigned dD, int p0) {
  uint4 u;
  u.x = bp(dA, dB, p0);       // e0,e1 (c=0,1 @ n)
  u.y = bp(dC, dD, p0);       // e2,e3 (c=2,3 @ n)
  u.z = bp(dA, dB, p0 + 1);   // e4,e5 (c=0,1 @ n+1)
  u.w = bp(dC, dD, p0 + 1);   // e6,e7 (c=2,3 @ n+1)
  return __builtin_bit_cast(bf16x8, u);
}

// K0: adj -> bitmask. Wave = one row pass; lane l reads int4 (4 j), 4
// ballots produce 256 j bits per iter. 8192 waves, 32 iters each, 32w/CU.
__global__ __launch_bounds__(256) void k0_bits(const int* __restrict__ adj,
    unsigned long long* __restrict__ bm) {
  const int w = threadIdx.x >> 6, l = threadIdx.x & 63;
  const int row = blockIdx.x * 4 + w;
  const int4* ar = (const int4*)(adj + (size_t)row * 8192) + l;
  unsigned long long* br = bm + (size_t)row * 128;
#pragma unroll 2
  for (int b = 0; b < 32; ++b) {
    int4 v = ar[b * 64];
    unsigned long long b0 = __ballot(v.x > 0);
    unsigned long long b1 = __ballot(v.y > 0);
    unsigned long long b2 = __ballot(v.z > 0);
    unsigned long long b3 = __ballot(v.w > 0);
    if (l == 0) {
      ulonglong2* p = (ulonglong2*)(br + (size_t)b * 4);
      p[0] = make_ulonglong2(b0, b1);
      p[1] = make_ulonglong2(b2, b3);
    }
  }
}

// K1a: WT[n][k] = bf16(W[k][n]); W is 512x256 row-major. Also zeroes T.
__global__ void k1a_wt(const float* __restrict__ W, unsigned short* __restrict__ WT,
                       float* __restrict__ T) {
  const int i = blockIdx.x * 256 + threadIdx.x;
  const int k = i >> 8, n = i & 255;
  WT[n * 512 + k] = f2bf(W[i]);
  if (blockIdx.x == 0) T[threadIdx.x] = 0.f;
}

// K1b: h = x @ W. x tile (32 rows x 512 k) staged through LDS in
// fragment-ready bf16 layout, then 32 MFMA k-steps.
__global__ __launch_bounds__(256) void k1b_h(const float* __restrict__ x,
    const unsigned short* __restrict__ WT, unsigned short* __restrict__ hP) {
  __shared__ unsigned short XS[64 * 264];
  const int t = threadIdx.x;
  const int mt = blockIdx.x;
  const int m0 = mt << 5;
  const int row = t >> 3, c7 = t & 7;
  const float* xr = x + (size_t)(m0 + row) * 512 + c7 * 4;
  const int gb = c7 >> 1, off = (t & 1) * 4;
#pragma unroll
  for (int j = 0; j < 16; ++j) {
    float4 v = *(const float4*)(xr + 32 * j);
    *(uint2*)&XS[(gb + 4 * j) * 264 + row * 8 + off] =
        make_uint2(pk2(v.x, v.y), pk2(v.z, v.w));
  }
  __syncthreads();
  const int w = t >> 6, l = t & 63, l31 = l & 31, lh = l >> 5;
  f32x16 acc0, acc1;
  for (int i = 0; i < 16; ++i) { acc0[i] = 0.f; acc1[i] = 0.f; }
  const int nt0 = w * 2;
  const unsigned short* w0 = WT + (size_t)(nt0 * 32 + l31) * 512 + lh * 8;
  const unsigned short* w1 = w0 + 32 * 512;
  const char* XB = (const char*)XS + lh * 528 + l31 * 16;
#pragma unroll 4
  for (int ks = 0; ks < 32; ++ks) {
    bf16x8 Af = *(const bf16x8*)(XB + ks * 1056);
    int4 b0 = *(const int4*)(w0 + ks * 16);
    int4 b1 = *(const int4*)(w1 + ks * 16);
    acc0 = mfma(Af, b0, acc0);
    acc1 = mfma(Af, b1, acc1);
  }
#pragma unroll
  for (int reg = 0; reg < 16; ++reg) {
    const int mm = (reg & 3) + 8 * (reg >> 2) + 4 * lh;      // C/D row map
    hP[(size_t)mt * 8192 + (nt0 * 32 + l31) * 32 + mm] = f2bf(acc0[reg]);
    hP[(size_t)mt * 8192 + ((nt0 + 1) * 32 + l31) * 32 + mm] = f2bf(acc1[reg]);
  }
}

// K2: T[n] += partial colsum of h. Block b sums panel block b (coalesced).
__global__ __launch_bounds__(256) void k2_colsum(const unsigned short* __restrict__ hP,
                                                 float* __restrict__ T) {
  const int t = threadIdx.x;
  const int b = blockIdx.x;
  const int4* p = (const int4*)(hP + (size_t)b * 8192 + t * 32);
  int4 q0 = p[0], q1 = p[1], q2 = p[2], q3 = p[3];
  float s = 0.f;
  const unsigned* u0 = (const unsigned*)&q0;
  const unsigned* u1 = (const unsigned*)&q1;
  const unsigned* u2 = (const unsigned*)&q2;
  const unsigned* u3 = (const unsigned*)&q3;
#pragma unroll
  for (int i = 0; i < 4; ++i) {
    s += bfbits2f(u0[i] & 0xFFFFu) + bfbits2f(u0[i] >> 16);
    s += bfbits2f(u1[i] & 0xFFFFu) + bfbits2f(u1[i] >> 16);
    s += bfbits2f(u2[i] & 0xFFFFu) + bfbits2f(u2[i] >> 16);
    s += bfbits2f(u3[i] & 0xFFFFu) + bfbits2f(u3[i] >> 16);
  }
  atomicAdd(&T[t], s);
}

// K3: out = -9e15*(T - (adj>0)@h). Grid 256 WG x 256 thr (1/CU).
// WG = 64 rows x 128 cols; waves: ch = col-half (64c), s = j-split (4096 j).
// Wave = 64r x 64c: acc[2][2] f32x16; 128 iters of 32 j. A-frags expanded
// in registers from bitmask blocks (32B per 8 iters per row-set, ping-pong
// prefetched one block ahead); B int4s from L2-hot hP, double-buffered.
// Epilogue: s=1 dumps acc to LDS, s=0 combines and writes out with T term.
__global__ __launch_bounds__(256, 1) void k3_att(
    const unsigned long long* __restrict__ bm,
    const unsigned short* __restrict__ hP, const float* __restrict__ T,
    float* __restrict__ out) {
  __shared__ float red[2][64][64];   // 32KB, epilogue only
  const int t = threadIdx.x, blk = blockIdx.x;
  const int w = t >> 6, l = t & 63, l31 = l & 31, lh = l >> 5;
  const int ch = w & 1, s = w >> 1;
  const int rb = blk >> 1, cb = blk & 1;
  const int r0 = rb * 64;
  const int cw0 = cb * 128 + ch * 64;
  const int lh2 = lh * 2;

  // bitmask: row r0+l31 (mt0) and r0+32+l31 (mt1); int4 units: row*64, s*32
  const int4* bmp0 = (const int4*)bm + (size_t)(r0 + l31) * 64 + s * 32;
  const int4* bmp1 = bmp0 + 32 * 64;
  // B-frag base: col (cw0+l31), k-half lh; + jt*8192; nt at +1024; ks at +16
  const unsigned short* hB = hP + (size_t)(cw0 + l31) * 32 + lh * 8;

  f32x16 acc[2][2];
#pragma unroll
  for (int mt = 0; mt < 2; ++mt)
#pragma unroll
    for (int nt = 0; nt < 2; ++nt)
#pragma unroll
      for (int i = 0; i < 16; ++i) acc[mt][nt][i] = 0.f;

  int4 qA0[2], qA1[2], qB0[2], qB1[2], BvA[4], BvB[4];
  int jt = s * 128;

#define LOADBM(k, Q0, Q1)                                                   \
  Q0[0] = bmp0[(k) * 2]; Q0[1] = bmp0[(k) * 2 + 1];                         \
  Q1[0] = bmp1[(k) * 2]; Q1[1] = bmp1[(k) * 2 + 1];

  // one j-iter: prefetch B(jt+1) into BVN, expand A from block dwords
  // (m = it&7 compile-time), 8 MFMA with BVC. OOB prefetch at jt=255 lands
  // in workspace padding (unused values) - safe.
#define ITER(mm, Q0, Q1, BVC, BVN)                                          \
  {                                                                         \
    {                                                                       \
      const unsigned short* hb_ = hB + (size_t)(jt + 1) * 8192;             \
      BVN[0] = *(const int4*)(hb_);                                         \
      BVN[1] = *(const int4*)(hb_ + 16);                                    \
      BVN[2] = *(const int4*)(hb_ + 1024);                                  \
      BVN[3] = *(const int4*)(hb_ + 1040);                                  \
    }                                                                       \
    const unsigned* q0_ = (const unsigned*)(Q0);                            \
    const unsigned* q1_ = (const unsigned*)(Q1);                            \
    const unsigned a0_ = q0_[((mm) >> 2)];                                  \
    const unsigned b0_ = q0_[2 + ((mm) >> 2)];                              \
    const unsigned c0_ = q0_[4 + ((mm) >> 2)];                              \
    const unsigned d0_ = q0_[6 + ((mm) >> 2)];                              \
    const unsigned a1_ = q1_[((mm) >> 2)];                                  \
    const unsigned b1_ = q1_[2 + ((mm) >> 2)];                              \
    const unsigned c1_ = q1_[4 + ((mm) >> 2)];                              \
    const unsigned d1_ = q1_[6 + ((mm) >> 2)];                              \
    const int pb_ = 8 * ((mm) & 3) + lh2;                                   \
    bf16x8 A00 = mkfrag(a0_, b0_, c0_, d0_, pb_);      /* mt0 ks0 */        \
    bf16x8 A01 = mkfrag(a0_, b0_, c0_, d0_, pb_ + 4);  /* mt0 ks1 */        \
    bf16x8 A10 = mkfrag(a1_, b1_, c1_, d1_, pb_);      /* mt1 ks0 */        \
    bf16x8 A11 = mkfrag(a1_, b1_, c1_, d1_, pb_ + 4);  /* mt1 ks1 */        \
    acc[0][0] = mfma(A00, BVC[0], acc[0][0]);                               \
    acc[1][0] = mfma(A10, BVC[0], acc[1][0]);                               \
    acc[0][1] = mfma(A00, BVC[2], acc[0][1]);                               \
    acc[1][1] = mfma(A10, BVC[2], acc[1][1]);                               \
    acc[0][0] = mfma(A01, BVC[1], acc[0][0]);                               \
    acc[1][0] = mfma(A11, BVC[1], acc[1][0]);                               \
    acc[0][1] = mfma(A01, BVC[3], acc[0][1]);                               \
    acc[1][1] = mfma(A11, BVC[3], acc[1][1]);                               \
    ++jt;                                                                   \
  }

  LOADBM(0, qA0, qA1)
  {
    const unsigned short* hb_ = hB + (size_t)jt * 8192;
    BvA[0] = *(const int4*)(hb_);
    BvA[1] = *(const int4*)(hb_ + 16);
    BvA[2] = *(const int4*)(hb_ + 1024);
    BvA[3] = *(const int4*)(hb_ + 1040);
  }

#pragma unroll 1
  for (int bb = 0; bb < 8; ++bb) {
    LOADBM(bb * 2 + 1, qB0, qB1)          // next block (used in 2nd half)
    ITER(0, qA0, qA1, BvA, BvB)
    ITER(1, qA0, qA1, BvB, BvA)
    ITER(2, qA0, qA1, BvA, BvB)
    ITER(3, qA0, qA1, BvB, BvA)
    ITER(4, qA0, qA1, BvA, BvB)
    ITER(5, qA0, qA1, BvB, BvA)
    ITER(6, qA0, qA1, BvA, BvB)
    ITER(7, qA0, qA1, BvB, BvA)
    LOADBM(bb * 2 + 2, qA0, qA1)          // block for next bb (OOB-safe @16)
    ITER(0, qB0, qB1, BvA, BvB)
    ITER(1, qB0, qB1, BvB, BvA)
    ITER(2, qB0, qB1, BvA, BvB)
    ITER(3, qB0, qB1, BvB, BvA)
    ITER(4, qB0, qB1, BvA, BvB)
    ITER(5, qB0, qB1, BvB, BvA)
    ITER(6, qB0, qB1, BvA, BvB)
    ITER(7, qB0, qB1, BvB, BvA)
  }
#undef ITER
#undef LOADBM

  // epilogue: combine j-splits via LDS, write out = -9e15*(T - Am)
  if (s == 1) {
#pragma unroll
    for (int mt = 0; mt < 2; ++mt)
#pragma unroll
      for (int nt = 0; nt < 2; ++nt)
#pragma unroll
        for (int reg = 0; reg < 16; ++reg)
          red[ch][(mt * 2 + nt) * 16 + reg][l] = acc[mt][nt][reg];
  }
  __syncthreads();
  if (s == 0) {
#pragma unroll
    for (int mt = 0; mt < 2; ++mt)
#pragma unroll
      for (int nt = 0; nt < 2; ++nt) {
        const int cc = cw0 + nt * 32 + l31;
        const float tv = T[cc];
#pragma unroll
        for (int reg = 0; reg < 16; ++reg) {
          const float am = acc[mt][nt][reg] + red[ch][(mt * 2 + nt) * 16 + reg][l];
          const int rr = r0 + mt * 32 + (reg & 3) + 8 * (reg >> 2) + 4 * lh;
          out[(size_t)rr * 256 + cc] = NEG_BIG * (tv - am);
        }
      }
  }
}

extern "C" void kernel_launch(void* const* d_in, const int* in_sizes, int n_in,
                              void* d_out, int out_size, void* d_ws, size_t ws_size,
                              hipStream_t stream) {
  const float* x = (const float*)d_in[0];     // 8192 x 512
  const float* W = (const float*)d_in[1];     // 512 x 256
  // d_in[2] ('a') unused: its contribution is ~1e4 vs threshold ~9e16.
  const int* adj = (const int*)d_in[3];       // 8192 x 8192 int32 {0,1}
  float* out = (float*)d_out;                 // 8192 x 256 fp32
  char* ws = (char*)d_ws;
  unsigned short* WT = (unsigned short*)(ws);             // 256 KB
  unsigned short* hP = (unsigned short*)(ws + (1 << 20)); // 4 MB panel
  float* T = (float*)(ws + (6 << 20));                    // 1 KB
  unsigned long long* bm = (unsigned long long*)(ws + (8 << 20)); // 8 MB

  k0_bits<<<2048, 256, 0, stream>>>(adj, bm);
  k1a_wt<<<512, 256, 0, stream>>>(W, WT, T);
  k1b_h<<<256, 256, 0, stream>>>(x, WT, hP);
  k2_colsum<<<256, 256, 0, stream>>>(hP, T);
  k3_att<<<256, 256, 0, stream>>>(bm, hP, T, out);
}

// Round 3
// 441.251 us; speedup vs baseline: 1.1119x; 1.0017x over previous
//
#include <hip/hip_runtime.h>

// out = att @ h  with att = where(adj>0, s1[i]+s2[j], -9e15).
// out[i,k] = -9e15 * (T[k] - Am[i,k]),  Am = (adj>0) @ h,  T = colsum(h)
//
// R9: R8's k3 ran ~100us at 1 wave/SIMD (no TLP; 112 VALU/iter expansion).
// Two fixes:
//  - splitK=4 in-WG: grid 512 WGs (2/CU) = 2 waves/SIMD; 48KB LDS reduce.
//  - cheap bit expansion: k1b writes hP with slot permutation
//    slot(mm) = ((mm>>1)&1)*16 + (mm&1)*8 + (mm>>2) so that each A-frag's
//    8 elements are 8 CONSECUTIVE bits of ONE ballot dword (c = ks*2+lh):
//    bb=(dw>>8m)&0xFF; t=bb|(bb<<15); u_e=((t>>2e)&0x10001)*0x3F80.
//    ~60 VALU/iter (was 112), and each lane loads only its lh's bm dwords
//    (2x dwordx2 per block, compile-time .x/.y selects).
//
// Bitmask format (per row, 32 blocks of 256 j): block b = 4 u64 [c=0..3],
// bit l of u64 c = adj[i][b*256 + 4l + c]  (ballot over int4 lanes).

#define NEG_BIG (-9000000000000000.0f)

typedef __bf16 bf16x8 __attribute__((ext_vector_type(8)));
typedef float f32x16 __attribute__((ext_vector_type(16)));

static __device__ __forceinline__ unsigned short f2bf(float f) {
  unsigned u = __builtin_bit_cast(unsigned, f);
  u = u + 0x7FFFu + ((u >> 16) & 1u);   // RNE
  return (unsigned short)(u >> 16);
}
static __device__ __forceinline__ float bfbits2f(unsigned hi16) {
  return __builtin_bit_cast(float, hi16 << 16);
}
static __device__ __forceinline__ unsigned pk2(float a, float b) {
  return (unsigned)f2bf(a) | ((unsigned)f2bf(b) << 16);
}
static __device__ __forceinline__ bf16x8 asbf(int4 q) {
  return __builtin_bit_cast(bf16x8, q);
}
static __device__ __forceinline__ f32x16 mfma(bf16x8 a, int4 b, f32x16 c) {
  return __builtin_amdgcn_mfma_f32_32x32x16_bf16(a, asbf(b), c, 0, 0, 0);
}

// K0: adj -> bitmask. Wave = one row pass; lane l reads int4 (4 j), 4
// ballots produce 256 j bits per iter. 8192 waves, 32 iters each, 32w/CU.
__global__ __launch_bounds__(256) void k0_bits(const int* __restrict__ adj,
    unsigned long long* __restrict__ bm) {
  const int w = threadIdx.x >> 6, l = threadIdx.x & 63;
  const int row = blockIdx.x * 4 + w;
  const int4* ar = (const int4*)(adj + (size_t)row * 8192) + l;
  unsigned long long* br = bm + (size_t)row * 128;
#pragma unroll 2
  for (int b = 0; b < 32; ++b) {
    int4 v = ar[b * 64];
    unsigned long long b0 = __ballot(v.x > 0);
    unsigned long long b1 = __ballot(v.y > 0);
    unsigned long long b2 = __ballot(v.z > 0);
    unsigned long long b3 = __ballot(v.w > 0);
    if (l == 0) {
      ulonglong2* p = (ulonglong2*)(br + (size_t)b * 4);
      p[0] = make_ulonglong2(b0, b1);
      p[1] = make_ulonglong2(b2, b3);
    }
  }
}

// K1a: WT[n][k] = bf16(W[k][n]); W is 512x256 row-major. Also zeroes T.
__global__ void k1a_wt(const float* __restrict__ W, unsigned short* __restrict__ WT,
                       float* __restrict__ T) {
  const int i = blockIdx.x * 256 + threadIdx.x;
  const int k = i >> 8, n = i & 255;
  WT[n * 512 + k] = f2bf(W[i]);
  if (blockIdx.x == 0) T[threadIdx.x] = 0.f;
}

// K1b: h = x @ W. x tile (32 rows x 512 k) staged through LDS in
// fragment-ready bf16 layout, then 32 MFMA k-steps. Panel slots are
// PERMUTED: physical row mm -> slot ((mm>>1)&1)*16 + (mm&1)*8 + (mm>>2)
// so k3's A-frag = consecutive bits of one ballot dword.
__global__ __launch_bounds__(256) void k1b_h(const float* __restrict__ x,
    const unsigned short* __restrict__ WT, unsigned short* __restrict__ hP) {
  __shared__ unsigned short XS[64 * 264];
  const int t = threadIdx.x;
  const int mt = blockIdx.x;
  const int m0 = mt << 5;
  const int row = t >> 3, c7 = t & 7;
  const float* xr = x + (size_t)(m0 + row) * 512 + c7 * 4;
  const int gb = c7 >> 1, off = (t & 1) * 4;
#pragma unroll
  for (int j = 0; j < 16; ++j) {
    float4 v = *(const float4*)(xr + 32 * j);
    *(uint2*)&XS[(gb + 4 * j) * 264 + row * 8 + off] =
        make_uint2(pk2(v.x, v.y), pk2(v.z, v.w));
  }
  __syncthreads();
  const int w = t >> 6, l = t & 63, l31 = l & 31, lh = l >> 5;
  f32x16 acc0, acc1;
  for (int i = 0; i < 16; ++i) { acc0[i] = 0.f; acc1[i] = 0.f; }
  const int nt0 = w * 2;
  const unsigned short* w0 = WT + (size_t)(nt0 * 32 + l31) * 512 + lh * 8;
  const unsigned short* w1 = w0 + 32 * 512;
  const char* XB = (const char*)XS + lh * 528 + l31 * 16;
#pragma unroll 4
  for (int ks = 0; ks < 32; ++ks) {
    bf16x8 Af = *(const bf16x8*)(XB + ks * 1056);
    int4 b0 = *(const int4*)(w0 + ks * 16);
    int4 b1 = *(const int4*)(w1 + ks * 16);
    acc0 = mfma(Af, b0, acc0);
    acc1 = mfma(Af, b1, acc1);
  }
#pragma unroll
  for (int reg = 0; reg < 16; ++reg) {
    const int mm = (reg & 3) + 8 * (reg >> 2) + 4 * lh;      // C/D row map
    const int sl = ((mm >> 1) & 1) * 16 + (mm & 1) * 8 + (mm >> 2);
    hP[(size_t)mt * 8192 + (nt0 * 32 + l31) * 32 + sl] = f2bf(acc0[reg]);
    hP[(size_t)mt * 8192 + ((nt0 + 1) * 32 + l31) * 32 + sl] = f2bf(acc1[reg]);
  }
}

// K2: T[n] += partial colsum of h (slot-permutation invariant).
__global__ __launch_bounds__(256) void k2_colsum(const unsigned short* __restrict__ hP,
                                                 float* __restrict__ T) {
  const int t = threadIdx.x;
  const int b = blockIdx.x;
  const int4* p = (const int4*)(hP + (size_t)b * 8192 + t * 32);
  int4 q0 = p[0], q1 = p[1], q2 = p[2], q3 = p[3];
  float s = 0.f;
  const unsigned* u0 = (const unsigned*)&q0;
  const unsigned* u1 = (const unsigned*)&q1;
  const unsigned* u2 = (const unsigned*)&q2;
  const unsigned* u3 = (const unsigned*)&q3;
#pragma unroll
  for (int i = 0; i < 4; ++i) {
    s += bfbits2f(u0[i] & 0xFFFFu) + bfbits2f(u0[i] >> 16);
    s += bfbits2f(u1[i] & 0xFFFFu) + bfbits2f(u1[i] >> 16);
    s += bfbits2f(u2[i] & 0xFFFFu) + bfbits2f(u2[i] >> 16);
    s += bfbits2f(u3[i] & 0xFFFFu) + bfbits2f(u3[i] >> 16);
  }
  atomicAdd(&T[t], s);
}

// K3: out = -9e15*(T - (adj>0)@h). Grid 512 WG x 256 thr (2 WG/CU).
// WG = tile 64r x 64c; 4 waves = splitK=4 (wave s: j in [s*2048,+2048),
// 64 iters of 32 j). A-frags expanded in registers from bitmask (each lane
// loads only its lh's dwords); B int4s from L2-hot hP, double-buffered.
// Epilogue: waves 1-3 dump acc to LDS (48KB), wave 0 combines + T + write.
__global__ __launch_bounds__(256, 2) void k3_att(
    const unsigned long long* __restrict__ bm,
    const unsigned short* __restrict__ hP, const float* __restrict__ T,
    float* __restrict__ out) {
  __shared__ float red[3][64][64];   // 48KB, epilogue only
  const int t = threadIdx.x, blk = blockIdx.x;
  const int w = t >> 6, l = t & 63, l31 = l & 31, lh = l >> 5;
  const int s = w;                   // j-split 0..3
  const int rb = blk >> 2, cb = blk & 3;
  const int r0 = rb * 64;
  const int cw0 = cb * 64;

  // bm row bases (bytes): row r0+l31 (rt0), r0+32+l31 (rt1); 1KB/row.
  // Within a 32B block: c = lh u64 at +lh*8 (ks0), c = 2+lh at +16+lh*8.
  const char* bmr0 = (const char*)bm + (size_t)(r0 + l31) * 1024 + s * 256 + lh * 8;
  const char* bmr1 = bmr0 + 32 * 1024;
  // B-frag base: col (cw0+l31), k-half lh; + jt*8192; n+32 at +1024; ks at +16
  const unsigned short* hB = hP + (size_t)(cw0 + l31) * 32 + lh * 8;

  f32x16 acc[2][2];
#pragma unroll
  for (int mt = 0; mt < 2; ++mt)
#pragma unroll
    for (int nt = 0; nt < 2; ++nt)
#pragma unroll
      for (int i = 0; i < 16; ++i) acc[mt][nt][i] = 0.f;

  uint2 pA0a, pA0b, pA1a, pA1b, pB0a, pB0b, pB1a, pB1b;
  int4 BvA[4], BvB[4];
  int jt = s * 64;

#define LOADBM(k, A0a, A0b, A1a, A1b)                                       \
  A0a = *(const uint2*)(bmr0 + (k) * 32);                                   \
  A0b = *(const uint2*)(bmr0 + (k) * 32 + 16);                              \
  A1a = *(const uint2*)(bmr1 + (k) * 32);                                   \
  A1b = *(const uint2*)(bmr1 + (k) * 32 + 16);

// expand 8 consecutive bits (byte m3) of dword dw -> 8 bf16 {0,1} (uint4)
#define XP(dw, m3, u4)                                                      \
  {                                                                         \
    const unsigned bb_ = ((dw) >> (8 * (m3))) & 0xFFu;                      \
    const unsigned tt_ = bb_ | (bb_ << 15);                                 \
    u4.x = ((tt_)&0x00010001u) * 0x3F80u;                                   \
    u4.y = ((tt_ >> 2) & 0x00010001u) * 0x3F80u;                            \
    u4.z = ((tt_ >> 4) & 0x00010001u) * 0x3F80u;                            \
    u4.w = ((tt_ >> 6) & 0x00010001u) * 0x3F80u;                            \
  }

  // one j-iter: prefetch B(jt+1) into BVN, expand 4 A-frags, 8 MFMA with
  // BVC. Final prefetch (jt=255 -> 256) reads ws padding below T - safe.
#define ITER(mm, A0a, A0b, A1a, A1b, BVC, BVN)                              \
  {                                                                         \
    {                                                                       \
      const unsigned short* hb_ = hB + (size_t)(jt + 1) * 8192;             \
      BVN[0] = *(const int4*)(hb_);                                         \
      BVN[1] = *(const int4*)(hb_ + 16);                                    \
      BVN[2] = *(const int4*)(hb_ + 1024);                                  \
      BVN[3] = *(const int4*)(hb_ + 1040);                                  \
    }                                                                       \
    const unsigned d00_ = ((mm) >> 2) ? A0a.y : A0a.x;  /* rt0 ks0 */       \
    const unsigned d01_ = ((mm) >> 2) ? A0b.y : A0b.x;  /* rt0 ks1 */       \
    const unsigned d10_ = ((mm) >> 2) ? A1a.y : A1a.x;  /* rt1 ks0 */       \
    const unsigned d11_ = ((mm) >> 2) ? A1b.y : A1b.x;  /* rt1 ks1 */       \
    uint4 u00_, u01_, u10_, u11_;                                           \
    XP(d00_, (mm)&3, u00_)                                                  \
    XP(d01_, (mm)&3, u01_)                                                  \
    XP(d10_, (mm)&3, u10_)                                                  \
    XP(d11_, (mm)&3, u11_)                                                  \
    const bf16x8 A00_ = __builtin_bit_cast(bf16x8, u00_);                   \
    const bf16x8 A01_ = __builtin_bit_cast(bf16x8, u01_);                   \
    const bf16x8 A10_ = __builtin_bit_cast(bf16x8, u10_);                   \
    const bf16x8 A11_ = __builtin_bit_cast(bf16x8, u11_);                   \
    acc[0][0] = mfma(A00_, BVC[0], acc[0][0]);                              \
    acc[1][0] = mfma(A10_, BVC[0], acc[1][0]);                              \
    acc[0][1] = mfma(A00_, BVC[2], acc[0][1]);                              \
    acc[1][1] = mfma(A10_, BVC[2], acc[1][1]);                              \
    acc[0][0] = mfma(A01_, BVC[1], acc[0][0]);                              \
    acc[1][0] = mfma(A11_, BVC[1], acc[1][0]);                              \
    acc[0][1] = mfma(A01_, BVC[3], acc[0][1]);                              \
    acc[1][1] = mfma(A11_, BVC[3], acc[1][1]);                              \
    ++jt;                                                                   \
  }

  LOADBM(0, pA0a, pA0b, pA1a, pA1b)
  {
    const unsigned short* hb_ = hB + (size_t)jt * 8192;
    BvA[0] = *(const int4*)(hb_);
    BvA[1] = *(const int4*)(hb_ + 16);
    BvA[2] = *(const int4*)(hb_ + 1024);
    BvA[3] = *(const int4*)(hb_ + 1040);
  }

#pragma unroll 1
  for (int b2 = 0; b2 < 8; b2 += 2) {
    LOADBM(b2 + 1, pB0a, pB0b, pB1a, pB1b)
    ITER(0, pA0a, pA0b, pA1a, pA1b, BvA, BvB)
    ITER(1, pA0a, pA0b, pA1a, pA1b, BvB, BvA)
    ITER(2, pA0a, pA0b, pA1a, pA1b, BvA, BvB)
    ITER(3, pA0a, pA0b, pA1a, pA1b, BvB, BvA)
    ITER(4, pA0a, pA0b, pA1a, pA1b, BvA, BvB)
    ITER(5, pA0a, pA0b, pA1a, pA1b, BvB, BvA)
    ITER(6, pA0a, pA0b, pA1a, pA1b, BvA, BvB)
    ITER(7, pA0a, pA0b, pA1a, pA1b, BvB, BvA)
    if (b2 + 2 < 8) { LOADBM(b2 + 2, pA0a, pA0b, pA1a, pA1b) }
    ITER(0, pB0a, pB0b, pB1a, pB1b, BvA, BvB)
    ITER(1, pB0a, pB0b, pB1a, pB1b, BvB, BvA)
    ITER(2, pB0a, pB0b, pB1a, pB1b, BvA, BvB)
    ITER(3, pB0a, pB0b, pB1a, pB1b, BvB, BvA)
    ITER(4, pB0a, pB0b, pB1a, pB1b, BvA, BvB)
    ITER(5, pB0a, pB0b, pB1a, pB1b, BvB, BvA)
    ITER(6, pB0a, pB0b, pB1a, pB1b, BvA, BvB)
    ITER(7, pB0a, pB0b, pB1a, pB1b, BvB, BvA)
  }
#undef ITER
#undef XP
#undef LOADBM

  // epilogue: splitK reduce via LDS, wave 0 writes out = -9e15*(T - Am)
  if (s > 0) {
#pragma unroll
    for (int mt = 0; mt < 2; ++mt)
#pragma unroll
      for (int nt = 0; nt < 2; ++nt)
#pragma unroll
        for (int reg = 0; reg < 16; ++reg)
          red[s - 1][(mt * 2 + nt) * 16 + reg][l] = acc[mt][nt][reg];
  }
  __syncthreads();
  if (s == 0) {
#pragma unroll
    for (int mt = 0; mt < 2; ++mt)
#pragma unroll
      for (int nt = 0; nt < 2; ++nt) {
        const int cc = cw0 + nt * 32 + l31;
        const float tv = T[cc];
#pragma unroll
        for (int reg = 0; reg < 16; ++reg) {
          const int idx = (mt * 2 + nt) * 16 + reg;
          const float am = acc[mt][nt][reg] + red[0][idx][l] +
                           red[1][idx][l] + red[2][idx][l];
          const int rr = r0 + mt * 32 + (reg & 3) + 8 * (reg >> 2) + 4 * lh;
          out[(size_t)rr * 256 + cc] = NEG_BIG * (tv - am);
        }
      }
  }
}

extern "C" void kernel_launch(void* const* d_in, const int* in_sizes, int n_in,
                              void* d_out, int out_size, void* d_ws, size_t ws_size,
                              hipStream_t stream) {
  const float* x = (const float*)d_in[0];     // 8192 x 512
  const float* W = (const float*)d_in[1];     // 512 x 256
  // d_in[2] ('a') unused: its contribution is ~1e4 vs threshold ~9e16.
  const int* adj = (const int*)d_in[3];       // 8192 x 8192 int32 {0,1}
  float* out = (float*)d_out;                 // 8192 x 256 fp32
  char* ws = (char*)d_ws;
  unsigned short* WT = (unsigned short*)(ws);             // 256 KB
  unsigned short* hP = (unsigned short*)(ws + (1 << 20)); // 4 MB panel
  float* T = (float*)(ws + (6 << 20));                    // 1 KB
  unsigned long long* bm = (unsigned long long*)(ws + (8 << 20)); // 8 MB

  k0_bits<<<2048, 256, 0, stream>>>(adj, bm);
  k1a_wt<<<512, 256, 0, stream>>>(W, WT, T);
  k1b_h<<<256, 256, 0, stream>>>(x, WT, hP);
  k2_colsum<<<256, 256, 0, stream>>>(hP, T);
  k3_att<<<512, 256, 0, stream>>>(bm, hP, T, out);
}